// Round 1
// 318.033 us; speedup vs baseline: 1.0818x; 1.0818x over previous
//
#include <hip/hip_runtime.h>
#include <hip/hip_fp16.h>

#define NDIM 64
#define RS 68      // LDS row stride in floats: 16B-aligned rows, conflict-free b128 frag reads
#define MAXNB 512  // supports N <= 131072 (bucket = dst>>8); this problem: N=100000 -> 391

typedef _Float16 h4 __attribute__((ext_vector_type(4)));
typedef float f4v __attribute__((ext_vector_type(4)));

// ---------------- BN fold + fragment-pack weights to split-fp16 ----------------
// Layout: Wpk[(l*2+m)][frag=ks*4+ct][lane][0..3]=hi j, [4..7]=lo j  (halfs)
// frag element: k = ks*16 + (lane>>4)*4 + j, col = ct*16 + (lane&15)
__global__ __launch_bounds__(256) void fold_pack_kernel(
    const float* __restrict__ W1, const float* __restrict__ b1,
    const float* __restrict__ gamma, const float* __restrict__ beta,
    const float* __restrict__ mean, const float* __restrict__ var,
    const float* __restrict__ W2,
    _Float16* __restrict__ Wpk, float* __restrict__ b1f)
{
    int l = blockIdx.x >> 1, m = blockIdx.x & 1;
    int t = threadIdx.x;
    const float* Wsrc = (m == 0 ? W1 : W2) + (size_t)l * 4096;
    if (m == 0 && t < 64) {
        float s = gamma[l * 64 + t] * rsqrtf(var[l * 64 + t] + 1e-5f);
        b1f[l * 64 + t] = (b1[l * 64 + t] - mean[l * 64 + t]) * s + beta[l * 64 + t];
    }
    int lane = t & 63;
    int c16 = lane & 15, kq = lane >> 4;
    for (int it = 0; it < 4; ++it) {
        int frag = it * 4 + (t >> 6);
        int ks = frag >> 2, ct = frag & 3;
        int col = ct * 16 + c16;
        int k0 = ks * 16 + kq * 4;
        float s = 1.f;
        if (m == 0) s = gamma[l * 64 + col] * rsqrtf(var[l * 64 + col] + 1e-5f);
        _Float16* dstp = Wpk + (((size_t)(l * 2 + m) * 16 + frag) * 64 + lane) * 8;
        for (int j = 0; j < 4; ++j) {
            float wv = Wsrc[(size_t)(k0 + j) * 64 + col] * s;
            _Float16 hi = (_Float16)wv;
            dstp[j] = hi;
            dstp[4 + j] = (_Float16)(wv - (float)hi);
        }
    }
}

// ---------------- x (fp32) -> fp16 rows for the gather ----------------
__global__ __launch_bounds__(256) void to_half_kernel(
    const float* __restrict__ x, __half* __restrict__ x16, int n4)
{
    int tid = blockIdx.x * blockDim.x + threadIdx.x;
    if (tid >= n4) return;
    float4 v = *(const float4*)(x + (size_t)tid * 4);
    __half2* dp = (__half2*)(x16 + (size_t)tid * 4);
    dp[0] = __floats2half2_rn(v.x, v.y);
    dp[1] = __floats2half2_rn(v.z, v.w);
}

// ---------------- CSR build, two-level LDS counting sort ----------------
__global__ __launch_bounds__(256) void bucket_count_kernel(
    const int* __restrict__ dst, int* __restrict__ bcnt, int E, int NBb)
{
    __shared__ int hist[MAXNB];
    for (int i = threadIdx.x; i < NBb; i += 256) hist[i] = 0;
    __syncthreads();
    int start = blockIdx.x * blockDim.x + threadIdx.x;
    int stride = gridDim.x * blockDim.x;
    for (int e = start; e < E; e += stride)
        atomicAdd(&hist[dst[e] >> 8], 1);          // LDS atomic: on-CU
    __syncthreads();
    for (int i = threadIdx.x; i < NBb; i += 256) {
        int v = hist[i];
        if (v) atomicAdd(&bcnt[i], v);
    }
}

__global__ __launch_bounds__(512) void bucket_scan_kernel(
    const int* __restrict__ bcnt, int* __restrict__ bbase,
    int* __restrict__ bcursor, int NBb)
{
    __shared__ int sd[512];
    int t = threadIdx.x;
    int v = (t < NBb) ? bcnt[t] : 0;
    sd[t] = v;
    __syncthreads();
    for (int d = 1; d < 512; d <<= 1) {
        int x = sd[t];
        int y = (t >= d) ? sd[t - d] : 0;
        __syncthreads();
        sd[t] = x + y;
        __syncthreads();
    }
    int excl = sd[t] - v;
    if (t < NBb) { bbase[t] = excl; bcursor[t] = excl; }
    if (t == NBb - 1) bbase[NBb] = sd[t];
}

__global__ __launch_bounds__(256) void bucket_scatter_kernel(
    const int* __restrict__ src, const int* __restrict__ dst,
    int* __restrict__ bcursor, unsigned int* __restrict__ packed, int E, int NBb)
{
    __shared__ int hist[MAXNB];
    __shared__ int sbase[MAXNB];
    for (int i = threadIdx.x; i < NBb; i += 256) hist[i] = 0;
    __syncthreads();
    int start = blockIdx.x * blockDim.x + threadIdx.x;
    int stride = gridDim.x * blockDim.x;
    for (int e = start; e < E; e += stride)
        atomicAdd(&hist[dst[e] >> 8], 1);
    __syncthreads();
    for (int i = threadIdx.x; i < NBb; i += 256) {
        int v = hist[i];
        sbase[i] = v ? atomicAdd(&bcursor[i], v) : 0;
    }
    __syncthreads();
    for (int i = threadIdx.x; i < NBb; i += 256) hist[i] = 0;  // reuse as cursor
    __syncthreads();
    for (int e = start; e < E; e += stride) {
        int d = dst[e];
        int b = d >> 8;
        int r = atomicAdd(&hist[b], 1);            // LDS rank
        packed[sbase[b] + r] = (unsigned)src[e] | ((unsigned)(d & 255) << 24);
    }
}

__global__ __launch_bounds__(256) void bucket_csr_kernel(
    const unsigned int* __restrict__ packed, const int* __restrict__ bbase,
    int* __restrict__ ssrc, int* __restrict__ offs, int* __restrict__ ends, int N)
{
    __shared__ int hist[256], scan[256], cur[256];
    int b = blockIdx.x;
    int base = bbase[b], cnt = bbase[b + 1] - base;
    int t = threadIdx.x;
    hist[t] = 0;
    __syncthreads();
    for (int i = t; i < cnt; i += 256)
        atomicAdd(&hist[packed[base + i] >> 24], 1);
    __syncthreads();
    int v = hist[t];
    scan[t] = v;
    __syncthreads();
    for (int d = 1; d < 256; d <<= 1) {
        int x = scan[t];
        int y = (t >= d) ? scan[t - d] : 0;
        __syncthreads();
        scan[t] = x + y;
        __syncthreads();
    }
    int e0 = base + scan[t] - v;
    cur[t] = e0;
    int node = b * 256 + t;
    if (node < N) { offs[node] = e0; ends[node] = e0 + v; }
    __syncthreads();
    for (int i = t; i < cnt; i += 256) {
        unsigned p = packed[base + i];
        int pos = atomicAdd(&cur[p >> 24], 1);
        ssrc[pos] = (int)(p & 0xFFFFFF);
    }
}

// ---------------- fused GIN layer: barrier-free, wave-owns-16-rows ----------------
__device__ inline float4 shfl_xor_f4(float4 v, int mask) {
    v.x = __shfl_xor(v.x, mask, 64);
    v.y = __shfl_xor(v.y, mask, 64);
    v.z = __shfl_xor(v.z, mask, 64);
    v.w = __shfl_xor(v.w, mask, 64);
    return v;
}

__device__ inline float4 load_h4(const __half* __restrict__ h, size_t row, int q) {
    const __half2* p = (const __half2*)(h + row * NDIM + q * 4);
    __half2 a = p[0], b = p[1];
    float2 fa = __half22float2(a), fb = __half22float2(b);
    return make_float4(fa.x, fa.y, fb.x, fb.y);
}

__global__ __launch_bounds__(256, 7) void gin_layer_kernel(
    const __half* __restrict__ hin, __half* __restrict__ hout,
    float* __restrict__ jk,
    const int* __restrict__ offs, const int* __restrict__ ends,
    const int* __restrict__ ssrc,
    const _Float16* __restrict__ w1p, const _Float16* __restrict__ w2p,
    const float* __restrict__ b1f, const float* __restrict__ b2,
    int N, int relu_out, int first, int write_h)
{
    __shared__ float lds[64 * RS];   // 17.4 KB: per-wave 16-row tile, reused pre->z->h
    int t = threadIdx.x;
    int lane = t & 63;
    int w = t >> 6;
    int row0 = blockIdx.x * 64;
    int wrow0 = row0 + w * 16;       // this wave's 16 rows
    if (wrow0 >= N) return;          // legal: no barriers anywhere in this kernel

    float* wtile = lds + (size_t)w * 16 * RS;

    // ---- per-wave CSR offsets via shuffle broadcast (no LDS, no sync) ----
    int offv = 0, endv = 0;
    if (lane < 16) {
        int node = wrow0 + lane;
        if (node < N) { offv = offs[node]; endv = ends[node]; }
    }

    // ---- gather phase: this wave produces its own 16 pre-rows ----
    int grp = lane >> 4;   // edge slot within a 4-edge bundle
    int q   = lane & 15;   // fp16x4 chunk of the row
    for (int i = 0; i < 16; ++i) {
        int node = wrow0 + i;
        if (node >= N) break;
        int beg = __shfl(offv, i, 64);
        int end = __shfl(endv, i, 64);

        float4 self = make_float4(0.f, 0.f, 0.f, 0.f);
        if (grp == 0) self = load_h4(hin, (size_t)node, q);

        float4 acc1 = make_float4(0.f, 0.f, 0.f, 0.f);
        float4 acc2 = make_float4(0.f, 0.f, 0.f, 0.f);
        for (int e = beg; e < end; e += 8) {
            int i1 = e + grp, i2 = e + grp + 4;
            int j1 = (i1 < end) ? ssrc[i1] : -1;
            int j2 = (i2 < end) ? ssrc[i2] : -1;
            if (j1 >= 0) {
                float4 v = load_h4(hin, (size_t)j1, q);
                acc1.x += v.x; acc1.y += v.y; acc1.z += v.z; acc1.w += v.w;
            }
            if (j2 >= 0) {
                float4 v = load_h4(hin, (size_t)j2, q);
                acc2.x += v.x; acc2.y += v.y; acc2.z += v.z; acc2.w += v.w;
            }
        }
        acc1.x += acc2.x; acc1.y += acc2.y; acc1.z += acc2.z; acc1.w += acc2.w;
        float4 o = shfl_xor_f4(acc1, 16);
        acc1.x += o.x; acc1.y += o.y; acc1.z += o.z; acc1.w += o.w;
        o = shfl_xor_f4(acc1, 32);
        acc1.x += o.x; acc1.y += o.y; acc1.z += o.z; acc1.w += o.w;

        if (grp == 0) {
            acc1.x += self.x; acc1.y += self.y; acc1.z += self.z; acc1.w += self.w;
            float* p = wtile + i * RS + q * 4;
            p[0] = acc1.x; p[1] = acc1.y; p[2] = acc1.z; p[3] = acc1.w;
        }
    }
    asm volatile("" ::: "memory");   // phase fence (same-wave DS is in-order in HW)

    // ---- MLP via MFMA, split-fp16 for ~fp32 accuracy ----
    // A: row=lane&15, k=4*(lane>>4)+j (+16*ks); B: col=lane&15, same k
    // C: row=(lane>>4)*4+reg, col=lane&15
    int lane15 = lane & 15;
    int lgrp = lane >> 4;
    const float* aRow = wtile + (size_t)lane15 * RS;
    const h4* W1 = (const h4*)w1p;
    const h4* W2 = (const h4*)w2p;
    f4v zero = {0.f, 0.f, 0.f, 0.f};
    f4v acc[4];

    // GEMM1: z = relu(pre @ W1f + b1f)
    #pragma unroll
    for (int ct = 0; ct < 4; ++ct) acc[ct] = zero;
    #pragma unroll
    for (int ks = 0; ks < 4; ++ks) {
        float4 av = *(const float4*)(aRow + ks * 16 + lgrp * 4);
        h4 ah, al;
        ah[0] = (_Float16)av.x; al[0] = (_Float16)(av.x - (float)ah[0]);
        ah[1] = (_Float16)av.y; al[1] = (_Float16)(av.y - (float)ah[1]);
        ah[2] = (_Float16)av.z; al[2] = (_Float16)(av.z - (float)ah[2]);
        ah[3] = (_Float16)av.w; al[3] = (_Float16)(av.w - (float)ah[3]);
        #pragma unroll
        for (int ct = 0; ct < 4; ++ct) {
            const h4* bp = W1 + (size_t)((ks * 4 + ct) * 64 + lane) * 2;
            h4 bh = bp[0], bl = bp[1];   // one dwordx4
            acc[ct] = __builtin_amdgcn_mfma_f32_16x16x16f16(ah, bh, acc[ct], 0, 0, 0);
            acc[ct] = __builtin_amdgcn_mfma_f32_16x16x16f16(al, bh, acc[ct], 0, 0, 0);
            acc[ct] = __builtin_amdgcn_mfma_f32_16x16x16f16(ah, bl, acc[ct], 0, 0, 0);
        }
    }
    asm volatile("" ::: "memory");
    #pragma unroll
    for (int ct = 0; ct < 4; ++ct) {
        int col = ct * 16 + lane15;
        float bb = b1f[col];
        #pragma unroll
        for (int i = 0; i < 4; ++i)
            wtile[(size_t)(lgrp * 4 + i) * RS + col] = fmaxf(acc[ct][i] + bb, 0.f);
    }
    asm volatile("" ::: "memory");

    // GEMM2: h = z @ W2 + b2 (+relu for non-final layers)
    #pragma unroll
    for (int ct = 0; ct < 4; ++ct) acc[ct] = zero;
    #pragma unroll
    for (int ks = 0; ks < 4; ++ks) {
        float4 av = *(const float4*)(aRow + ks * 16 + lgrp * 4);
        h4 ah, al;
        ah[0] = (_Float16)av.x; al[0] = (_Float16)(av.x - (float)ah[0]);
        ah[1] = (_Float16)av.y; al[1] = (_Float16)(av.y - (float)ah[1]);
        ah[2] = (_Float16)av.z; al[2] = (_Float16)(av.z - (float)ah[2]);
        ah[3] = (_Float16)av.w; al[3] = (_Float16)(av.w - (float)ah[3]);
        #pragma unroll
        for (int ct = 0; ct < 4; ++ct) {
            const h4* bp = W2 + (size_t)((ks * 4 + ct) * 64 + lane) * 2;
            h4 bh = bp[0], bl = bp[1];
            acc[ct] = __builtin_amdgcn_mfma_f32_16x16x16f16(ah, bh, acc[ct], 0, 0, 0);
            acc[ct] = __builtin_amdgcn_mfma_f32_16x16x16f16(al, bh, acc[ct], 0, 0, 0);
            acc[ct] = __builtin_amdgcn_mfma_f32_16x16x16f16(ah, bl, acc[ct], 0, 0, 0);
        }
    }
    asm volatile("" ::: "memory");
    #pragma unroll
    for (int ct = 0; ct < 4; ++ct) {
        int col = ct * 16 + lane15;
        float bb = b2[col];
        #pragma unroll
        for (int i = 0; i < 4; ++i) {
            float hv = acc[ct][i] + bb;
            if (relu_out) hv = fmaxf(hv, 0.f);
            wtile[(size_t)(lgrp * 4 + i) * RS + col] = hv;
        }
    }
    asm volatile("" ::: "memory");

    // ---- writeback: wave-local (16 rows x 16 f4-chunks = 256 chunks / 64 lanes) ----
    #pragma unroll
    for (int it = 0; it < 4; ++it) {
        int fl = it * 64 + lane;
        int r = fl >> 4, c4 = fl & 15;
        int grow = wrow0 + r;
        if (grow >= N) continue;
        const float* p = wtile + (size_t)r * RS + c4 * 4;
        float4 hv = make_float4(p[0], p[1], p[2], p[3]);
        if (write_h) {
            __half2* dp = (__half2*)(hout + (size_t)grow * NDIM + c4 * 4);
            dp[0] = __floats2half2_rn(hv.x, hv.y);
            dp[1] = __floats2half2_rn(hv.z, hv.w);
        }
        float4 jv;
        if (first) jv = hv;
        else {
            float4 o = *(const float4*)(jk + (size_t)grow * NDIM + c4 * 4);
            jv = make_float4(o.x + hv.x, o.y + hv.y, o.z + hv.z, o.w + hv.w);
        }
        *(float4*)(jk + (size_t)grow * NDIM + c4 * 4) = jv;
    }
}

extern "C" void kernel_launch(void* const* d_in, const int* in_sizes, int n_in,
                              void* d_out, int out_size, void* d_ws, size_t ws_size,
                              hipStream_t stream) {
    const float* x     = (const float*)d_in[0];
    const int*   src   = (const int*)  d_in[1];
    const int*   dst   = (const int*)  d_in[2];
    const float* W1    = (const float*)d_in[3];
    const float* b1    = (const float*)d_in[4];
    const float* gamma = (const float*)d_in[5];
    const float* beta  = (const float*)d_in[6];
    const float* mean  = (const float*)d_in[7];
    const float* var   = (const float*)d_in[8];
    const float* W2    = (const float*)d_in[9];
    const float* b2    = (const float*)d_in[10];

    int N = in_sizes[0] / NDIM;
    int E = in_sizes[1];
    int L = in_sizes[3] / (NDIM * NDIM);
    int NBb = (N + 255) >> 8;            // buckets of 256 nodes
    float* out = (float*)d_out;

    char* w = (char*)d_ws;
    size_t off = 0;
    auto carve = [&](size_t bytes) -> void* {
        void* p = w + off;
        off += (bytes + 255) & ~(size_t)255;
        return p;
    };
    __half* h16A    = (__half*)carve((size_t)N * NDIM * 2);   // ping
    __half* h16B    = (__half*)carve((size_t)N * NDIM * 2);   // pong
    int*    ssrc    = (int*)   carve((size_t)E * 4);
    unsigned int* packed = (unsigned int*)carve((size_t)E * 4);
    int*    offs    = (int*)   carve((size_t)N * 4);
    int*    ends    = (int*)   carve((size_t)N * 4);
    int*    bcnt    = (int*)   carve((size_t)(MAXNB + 1) * 4);
    int*    bbase   = (int*)   carve((size_t)(MAXNB + 1) * 4);
    int*    bcursor = (int*)   carve((size_t)MAXNB * 4);
    _Float16* Wpk   = (_Float16*)carve((size_t)L * 2 * 16 * 64 * 8 * 2);  // hi/lo packed frags
    float*  b1f     = (float*) carve((size_t)L * NDIM * 4);

    hipMemsetAsync(bcnt, 0, (size_t)(MAXNB + 1) * 4, stream);
    fold_pack_kernel<<<L * 2, 256, 0, stream>>>(
        W1, b1, gamma, beta, mean, var, W2, Wpk, b1f);
    to_half_kernel<<<(N * NDIM / 4 + 255) / 256, 256, 0, stream>>>(x, h16A, N * NDIM / 4);
    bucket_count_kernel<<<256, 256, 0, stream>>>(dst, bcnt, E, NBb);
    bucket_scan_kernel<<<1, 512, 0, stream>>>(bcnt, bbase, bcursor, NBb);
    bucket_scatter_kernel<<<256, 256, 0, stream>>>(src, dst, bcursor, packed, E, NBb);
    bucket_csr_kernel<<<NBb, 256, 0, stream>>>(packed, bbase, ssrc, offs, ends, N);

    const __half* hin = h16A;
    __half* hout = h16B;
    for (int l = 0; l < L; ++l) {
        gin_layer_kernel<<<(N + 63) / 64, 256, 0, stream>>>(
            hin, hout, out, offs, ends, ssrc,
            Wpk + (size_t)(l * 2 + 0) * 16 * 64 * 8,
            Wpk + (size_t)(l * 2 + 1) * 16 * 64 * 8,
            b1f + (size_t)l * NDIM, b2 + (size_t)l * NDIM,
            N, (l < L - 1) ? 1 : 0, (l == 0) ? 1 : 0, (l < L - 1) ? 1 : 0);
        const __half* tmp = hin;
        hin = hout;
        hout = (__half*)tmp;
    }
}

// Round 2
// 300.491 us; speedup vs baseline: 1.1450x; 1.0584x over previous
//
#include <hip/hip_runtime.h>
#include <hip/hip_fp16.h>

#define NDIM 64
#define RS 68      // LDS row stride in floats: 16B-aligned rows, conflict-free b128 frag reads
#define MAXNB 512  // supports N <= 131072 (bucket = dst>>8); this problem: N=100000 -> 391
#define CAP 6144   // padded per-bucket capacity (expected ~3072, +55 sigma headroom)
#define EBUF 352   // per-wave LDS edge-index buffer (16 rows, mean 192 edges, +11 sigma)

typedef _Float16 h4 __attribute__((ext_vector_type(4)));
typedef float f4v __attribute__((ext_vector_type(4)));

// ---------------- prep: BN-fold + split-fp16 weight pack, and x -> fp16 ----------------
// Wpk layout: [(l*2+m)][frag=ks*4+ct][lane][0..3]=hi j, [4..7]=lo j (halfs)
// frag element: k = ks*16 + (lane>>4)*4 + j, col = ct*16 + (lane&15)
__global__ __launch_bounds__(256) void prep_kernel(
    const float* __restrict__ x, __half* __restrict__ x16, int n4,
    const float* __restrict__ W1, const float* __restrict__ b1,
    const float* __restrict__ gamma, const float* __restrict__ beta,
    const float* __restrict__ mean, const float* __restrict__ var,
    const float* __restrict__ W2,
    _Float16* __restrict__ Wpk, float* __restrict__ b1f, int L)
{
    int bid = blockIdx.x;
    int t = threadIdx.x;
    if (bid < 2 * L) {
        int l = bid >> 1, m = bid & 1;
        const float* Wsrc = (m == 0 ? W1 : W2) + (size_t)l * 4096;
        if (m == 0 && t < 64) {
            float s = gamma[l * 64 + t] * rsqrtf(var[l * 64 + t] + 1e-5f);
            b1f[l * 64 + t] = (b1[l * 64 + t] - mean[l * 64 + t]) * s + beta[l * 64 + t];
        }
        int lane = t & 63;
        int c16 = lane & 15, kq = lane >> 4;
        for (int it = 0; it < 4; ++it) {
            int frag = it * 4 + (t >> 6);
            int ks = frag >> 2, ct = frag & 3;
            int col = ct * 16 + c16;
            int k0 = ks * 16 + kq * 4;
            float s = 1.f;
            if (m == 0) s = gamma[l * 64 + col] * rsqrtf(var[l * 64 + col] + 1e-5f);
            _Float16* dstp = Wpk + (((size_t)(l * 2 + m) * 16 + frag) * 64 + lane) * 8;
            for (int j = 0; j < 4; ++j) {
                float wv = Wsrc[(size_t)(k0 + j) * 64 + col] * s;
                _Float16 hi = (_Float16)wv;
                dstp[j] = hi;
                dstp[4 + j] = (_Float16)(wv - (float)hi);
            }
        }
        return;
    }
    int tid = (bid - 2 * L) * 256 + t;
    if (tid >= n4) return;
    float4 v = *(const float4*)(x + (size_t)tid * 4);
    __half2* dp = (__half2*)(x16 + (size_t)tid * 4);
    dp[0] = __floats2half2_rn(v.x, v.y);
    dp[1] = __floats2half2_rn(v.z, v.w);
}

// ---------------- single-pass bucket scatter into padded regions ----------------
__global__ __launch_bounds__(256) void bucket_scatter_kernel(
    const int* __restrict__ src, const int* __restrict__ dst,
    int* __restrict__ bcnt, unsigned int* __restrict__ packed, int E, int NBb)
{
    __shared__ int hist[MAXNB];
    __shared__ int sbase[MAXNB];
    for (int i = threadIdx.x; i < NBb; i += 256) hist[i] = 0;
    __syncthreads();
    int start = blockIdx.x * blockDim.x + threadIdx.x;
    int stride = gridDim.x * blockDim.x;
    for (int e = start; e < E; e += stride)
        atomicAdd(&hist[dst[e] >> 8], 1);          // LDS atomic: on-CU
    __syncthreads();
    for (int i = threadIdx.x; i < NBb; i += 256) {
        int v = hist[i];
        sbase[i] = v ? (i * CAP + atomicAdd(&bcnt[i], v)) : 0;
    }
    __syncthreads();
    for (int i = threadIdx.x; i < NBb; i += 256) hist[i] = 0;  // reuse as cursor
    __syncthreads();
    for (int e = start; e < E; e += stride) {
        int d = dst[e];
        int b = d >> 8;
        int r = atomicAdd(&hist[b], 1);            // LDS rank
        packed[sbase[b] + r] = (unsigned)src[e] | ((unsigned)(d & 255) << 24);
    }
}

// ---------------- per-bucket CSR finalize (inline exclusive prefix of bcnt) ----------------
__global__ __launch_bounds__(256) void bucket_csr_kernel(
    const unsigned int* __restrict__ packed, const int* __restrict__ bcnt,
    int* __restrict__ ssrc, int* __restrict__ offs, int* __restrict__ ends, int N)
{
    __shared__ int hist[256], scan[256], cur[256];
    __shared__ int swbase;
    int b = blockIdx.x;
    int t = threadIdx.x;
    // exclusive prefix: wbase = sum_{i<b} bcnt[i]
    int partial = 0;
    for (int i = t; i < b; i += 256) partial += bcnt[i];
    scan[t] = partial;
    hist[t] = 0;
    __syncthreads();
    for (int d = 128; d > 0; d >>= 1) {
        if (t < d) scan[t] += scan[t + d];
        __syncthreads();
    }
    if (t == 0) swbase = scan[0];
    __syncthreads();
    int wbase = swbase;
    int cnt = bcnt[b];
    if (cnt > CAP) cnt = CAP;
    size_t rbase = (size_t)b * CAP;
    for (int i = t; i < cnt; i += 256)
        atomicAdd(&hist[packed[rbase + i] >> 24], 1);
    __syncthreads();
    int v = hist[t];
    scan[t] = v;
    __syncthreads();
    for (int d = 1; d < 256; d <<= 1) {
        int x = scan[t];
        int y = (t >= d) ? scan[t - d] : 0;
        __syncthreads();
        scan[t] = x + y;
        __syncthreads();
    }
    int e0 = wbase + scan[t] - v;
    cur[t] = e0;
    int node = b * 256 + t;
    if (node < N) { offs[node] = e0; ends[node] = e0 + v; }
    __syncthreads();
    for (int i = t; i < cnt; i += 256) {
        unsigned p = packed[rbase + i];
        int pos = atomicAdd(&cur[p >> 24], 1);
        ssrc[pos] = (int)(p & 0xFFFFFF);
    }
}

// ---------------- fused GIN layer: barrier-free, wave-owns-16-rows ----------------
__device__ inline float4 shfl_xor_f4(float4 v, int mask) {
    v.x = __shfl_xor(v.x, mask, 64);
    v.y = __shfl_xor(v.y, mask, 64);
    v.z = __shfl_xor(v.z, mask, 64);
    v.w = __shfl_xor(v.w, mask, 64);
    return v;
}

__device__ inline void add4(float4& a, const float4& v) {
    a.x += v.x; a.y += v.y; a.z += v.z; a.w += v.w;
}

__device__ inline float4 load_h4(const __half* __restrict__ h, size_t row, int q) {
    uint2 u = *(const uint2*)(h + row * NDIM + q * 4);   // single 8B load
    __half2 a = __builtin_bit_cast(__half2, u.x);
    __half2 b = __builtin_bit_cast(__half2, u.y);
    float2 fa = __half22float2(a), fb = __half22float2(b);
    return make_float4(fa.x, fa.y, fb.x, fb.y);
}

__global__ __launch_bounds__(256, 7) void gin_layer_kernel(
    const __half* __restrict__ hin, __half* __restrict__ hout,
    float* __restrict__ jk,
    const int* __restrict__ offs, const int* __restrict__ ends,
    const int* __restrict__ ssrc,
    const _Float16* __restrict__ w1p, const _Float16* __restrict__ w2p,
    const float* __restrict__ b1f, const float* __restrict__ b2,
    int N, int relu_out, int first, int write_h)
{
    __shared__ float lds[64 * RS];       // 17408B: per-wave 16-row tile, reused pre->z->h
    __shared__ int ebuf_s[4 * EBUF];     // 5632B: per-wave edge-index prefetch
    int t = threadIdx.x;
    int lane = t & 63;
    int w = t >> 6;
    int row0 = blockIdx.x * 64;
    int wrow0 = row0 + w * 16;           // this wave's 16 rows
    if (wrow0 >= N) return;              // legal: no barriers anywhere in this kernel

    float* wtile = lds + (size_t)w * 16 * RS;
    int* ebuf = ebuf_s + w * EBUF;

    // ---- per-wave CSR offsets via shuffle broadcast (no sync) ----
    int offv = 0, endv = 0;
    if (lane < 16) {
        int node = wrow0 + lane;
        int cn = (node < N) ? node : (N - 1);
        offv = offs[cn];
        endv = ends[cn];
        if (node >= N) offv = endv;      // OOB rows -> empty, endv stays monotone
    }
    int begAll = __shfl(offv, 0, 64);
    int endAll = __shfl(endv, 15, 64);
    int cnt = endAll - begAll;

    // ---- prefetch this wave's contiguous edge-index slice into LDS (coalesced) ----
    bool useLds = (cnt <= EBUF);
    if (useLds) {
        for (int k = lane; k < cnt; k += 64) ebuf[k] = ssrc[begAll + k];
    }
    auto eidx = [&](int pos) -> int {
        return useLds ? ebuf[pos - begAll] : ssrc[pos];
    };

    // ---- gather phase: two rows in flight per iteration (2x MLP depth) ----
    int grp = lane >> 4;   // edge slot within a 4-edge bundle
    int q   = lane & 15;   // fp16x4 chunk of the row
    for (int i = 0; i < 16; i += 2) {
        int nodeA = wrow0 + i, nodeB = wrow0 + i + 1;
        int begA = __shfl(offv, i, 64),     endA = __shfl(endv, i, 64);
        int begB = __shfl(offv, i + 1, 64), endB = __shfl(endv, i + 1, 64);

        float4 selfA = make_float4(0.f, 0.f, 0.f, 0.f);
        float4 selfB = make_float4(0.f, 0.f, 0.f, 0.f);
        if (grp == 0) {
            if (nodeA < N) selfA = load_h4(hin, (size_t)nodeA, q);
            if (nodeB < N) selfB = load_h4(hin, (size_t)nodeB, q);
        }

        float4 aA1 = make_float4(0.f, 0.f, 0.f, 0.f);
        float4 aA2 = make_float4(0.f, 0.f, 0.f, 0.f);
        float4 aB1 = make_float4(0.f, 0.f, 0.f, 0.f);
        float4 aB2 = make_float4(0.f, 0.f, 0.f, 0.f);
        int eA = begA, eB = begB;
        while (eA < endA || eB < endB) {
            int jA1 = (eA + grp     < endA) ? eidx(eA + grp)     : -1;
            int jA2 = (eA + grp + 4 < endA) ? eidx(eA + grp + 4) : -1;
            int jB1 = (eB + grp     < endB) ? eidx(eB + grp)     : -1;
            int jB2 = (eB + grp + 4 < endB) ? eidx(eB + grp + 4) : -1;
            if (jA1 >= 0) { float4 v = load_h4(hin, (size_t)jA1, q); add4(aA1, v); }
            if (jA2 >= 0) { float4 v = load_h4(hin, (size_t)jA2, q); add4(aA2, v); }
            if (jB1 >= 0) { float4 v = load_h4(hin, (size_t)jB1, q); add4(aB1, v); }
            if (jB2 >= 0) { float4 v = load_h4(hin, (size_t)jB2, q); add4(aB2, v); }
            eA += 8; eB += 8;
        }
        // reduce row A (same order as before: acc1+acc2, xor16, xor32, +self)
        add4(aA1, aA2);
        float4 o = shfl_xor_f4(aA1, 16); add4(aA1, o);
        o = shfl_xor_f4(aA1, 32); add4(aA1, o);
        if (grp == 0) {
            add4(aA1, selfA);
            if (nodeA < N) {
                float* p = wtile + i * RS + q * 4;
                p[0] = aA1.x; p[1] = aA1.y; p[2] = aA1.z; p[3] = aA1.w;
            }
        }
        // reduce row B
        add4(aB1, aB2);
        o = shfl_xor_f4(aB1, 16); add4(aB1, o);
        o = shfl_xor_f4(aB1, 32); add4(aB1, o);
        if (grp == 0) {
            add4(aB1, selfB);
            if (nodeB < N) {
                float* p = wtile + (i + 1) * RS + q * 4;
                p[0] = aB1.x; p[1] = aB1.y; p[2] = aB1.z; p[3] = aB1.w;
            }
        }
    }
    asm volatile("" ::: "memory");   // phase fence (same-wave DS is in-order in HW)

    // ---- MLP via MFMA, split-fp16 for ~fp32 accuracy ----
    // A: row=lane&15, k=4*(lane>>4)+j (+16*ks); B: col=lane&15, same k
    // C: row=(lane>>4)*4+reg, col=lane&15
    int lane15 = lane & 15;
    int lgrp = lane >> 4;
    const float* aRow = wtile + (size_t)lane15 * RS;
    const h4* W1 = (const h4*)w1p;
    const h4* W2 = (const h4*)w2p;
    f4v zero = {0.f, 0.f, 0.f, 0.f};
    f4v acc[4];

    // GEMM1: z = relu(pre @ W1f + b1f)
    #pragma unroll
    for (int ct = 0; ct < 4; ++ct) acc[ct] = zero;
    #pragma unroll
    for (int ks = 0; ks < 4; ++ks) {
        float4 av = *(const float4*)(aRow + ks * 16 + lgrp * 4);
        h4 ah, al;
        ah[0] = (_Float16)av.x; al[0] = (_Float16)(av.x - (float)ah[0]);
        ah[1] = (_Float16)av.y; al[1] = (_Float16)(av.y - (float)ah[1]);
        ah[2] = (_Float16)av.z; al[2] = (_Float16)(av.z - (float)ah[2]);
        ah[3] = (_Float16)av.w; al[3] = (_Float16)(av.w - (float)ah[3]);
        #pragma unroll
        for (int ct = 0; ct < 4; ++ct) {
            const h4* bp = W1 + (size_t)((ks * 4 + ct) * 64 + lane) * 2;
            h4 bh = bp[0], bl = bp[1];   // one dwordx4
            acc[ct] = __builtin_amdgcn_mfma_f32_16x16x16f16(ah, bh, acc[ct], 0, 0, 0);
            acc[ct] = __builtin_amdgcn_mfma_f32_16x16x16f16(al, bh, acc[ct], 0, 0, 0);
            acc[ct] = __builtin_amdgcn_mfma_f32_16x16x16f16(ah, bl, acc[ct], 0, 0, 0);
        }
    }
    asm volatile("" ::: "memory");
    #pragma unroll
    for (int ct = 0; ct < 4; ++ct) {
        int col = ct * 16 + lane15;
        float bb = b1f[col];
        #pragma unroll
        for (int i = 0; i < 4; ++i)
            wtile[(size_t)(lgrp * 4 + i) * RS + col] = fmaxf(acc[ct][i] + bb, 0.f);
    }
    asm volatile("" ::: "memory");

    // GEMM2: h = z @ W2 + b2 (+relu for non-final layers)
    #pragma unroll
    for (int ct = 0; ct < 4; ++ct) acc[ct] = zero;
    #pragma unroll
    for (int ks = 0; ks < 4; ++ks) {
        float4 av = *(const float4*)(aRow + ks * 16 + lgrp * 4);
        h4 ah, al;
        ah[0] = (_Float16)av.x; al[0] = (_Float16)(av.x - (float)ah[0]);
        ah[1] = (_Float16)av.y; al[1] = (_Float16)(av.y - (float)ah[1]);
        ah[2] = (_Float16)av.z; al[2] = (_Float16)(av.z - (float)ah[2]);
        ah[3] = (_Float16)av.w; al[3] = (_Float16)(av.w - (float)ah[3]);
        #pragma unroll
        for (int ct = 0; ct < 4; ++ct) {
            const h4* bp = W2 + (size_t)((ks * 4 + ct) * 64 + lane) * 2;
            h4 bh = bp[0], bl = bp[1];
            acc[ct] = __builtin_amdgcn_mfma_f32_16x16x16f16(ah, bh, acc[ct], 0, 0, 0);
            acc[ct] = __builtin_amdgcn_mfma_f32_16x16x16f16(al, bh, acc[ct], 0, 0, 0);
            acc[ct] = __builtin_amdgcn_mfma_f32_16x16x16f16(ah, bl, acc[ct], 0, 0, 0);
        }
    }
    asm volatile("" ::: "memory");
    #pragma unroll
    for (int ct = 0; ct < 4; ++ct) {
        int col = ct * 16 + lane15;
        float bb = b2[col];
        #pragma unroll
        for (int i = 0; i < 4; ++i) {
            float hv = acc[ct][i] + bb;
            if (relu_out) hv = fmaxf(hv, 0.f);
            wtile[(size_t)(lgrp * 4 + i) * RS + col] = hv;
        }
    }
    asm volatile("" ::: "memory");

    // ---- writeback: wave-local (16 rows x 16 f4-chunks = 256 chunks / 64 lanes) ----
    #pragma unroll
    for (int it = 0; it < 4; ++it) {
        int fl = it * 64 + lane;
        int r = fl >> 4, c4 = fl & 15;
        int grow = wrow0 + r;
        if (grow >= N) continue;
        const float* p = wtile + (size_t)r * RS + c4 * 4;
        float4 hv = make_float4(p[0], p[1], p[2], p[3]);
        if (write_h) {
            __half2* dp = (__half2*)(hout + (size_t)grow * NDIM + c4 * 4);
            dp[0] = __floats2half2_rn(hv.x, hv.y);
            dp[1] = __floats2half2_rn(hv.z, hv.w);
        }
        float4 jv;
        if (first) jv = hv;
        else {
            float4 o = *(const float4*)(jk + (size_t)grow * NDIM + c4 * 4);
            jv = make_float4(o.x + hv.x, o.y + hv.y, o.z + hv.z, o.w + hv.w);
        }
        *(float4*)(jk + (size_t)grow * NDIM + c4 * 4) = jv;
    }
}

extern "C" void kernel_launch(void* const* d_in, const int* in_sizes, int n_in,
                              void* d_out, int out_size, void* d_ws, size_t ws_size,
                              hipStream_t stream) {
    const float* x     = (const float*)d_in[0];
    const int*   src   = (const int*)  d_in[1];
    const int*   dst   = (const int*)  d_in[2];
    const float* W1    = (const float*)d_in[3];
    const float* b1    = (const float*)d_in[4];
    const float* gamma = (const float*)d_in[5];
    const float* beta  = (const float*)d_in[6];
    const float* mean  = (const float*)d_in[7];
    const float* var   = (const float*)d_in[8];
    const float* W2    = (const float*)d_in[9];
    const float* b2    = (const float*)d_in[10];

    int N = in_sizes[0] / NDIM;
    int E = in_sizes[1];
    int L = in_sizes[3] / (NDIM * NDIM);
    int NBb = (N + 255) >> 8;            // buckets of 256 nodes
    int n4 = N * NDIM / 4;
    float* out = (float*)d_out;

    char* w = (char*)d_ws;
    size_t off = 0;
    auto carve = [&](size_t bytes) -> void* {
        void* p = w + off;
        off += (bytes + 255) & ~(size_t)255;
        return p;
    };
    __half* h16A    = (__half*)carve((size_t)N * NDIM * 2);   // ping
    __half* h16B    = (__half*)carve((size_t)N * NDIM * 2);   // pong
    int*    ssrc    = (int*)   carve((size_t)E * 4);
    unsigned int* packed = (unsigned int*)carve((size_t)NBb * CAP * 4);
    int*    offs    = (int*)   carve((size_t)N * 4);
    int*    ends    = (int*)   carve((size_t)N * 4);
    int*    bcnt    = (int*)   carve((size_t)(MAXNB + 1) * 4);
    _Float16* Wpk   = (_Float16*)carve((size_t)L * 2 * 16 * 64 * 8 * 2);  // hi/lo packed frags
    float*  b1f     = (float*) carve((size_t)L * NDIM * 4);

    hipMemsetAsync(bcnt, 0, (size_t)(MAXNB + 1) * 4, stream);
    prep_kernel<<<2 * L + (n4 + 255) / 256, 256, 0, stream>>>(
        x, h16A, n4, W1, b1, gamma, beta, mean, var, W2, Wpk, b1f, L);
    bucket_scatter_kernel<<<256, 256, 0, stream>>>(src, dst, bcnt, packed, E, NBb);
    bucket_csr_kernel<<<NBb, 256, 0, stream>>>(packed, bcnt, ssrc, offs, ends, N);

    const __half* hin = h16A;
    __half* hout = h16B;
    for (int l = 0; l < L; ++l) {
        gin_layer_kernel<<<(N + 63) / 64, 256, 0, stream>>>(
            hin, hout, out, offs, ends, ssrc,
            Wpk + (size_t)(l * 2 + 0) * 16 * 64 * 8,
            Wpk + (size_t)(l * 2 + 1) * 16 * 64 * 8,
            b1f + (size_t)l * NDIM, b2 + (size_t)l * NDIM,
            N, (l < L - 1) ? 1 : 0, (l == 0) ? 1 : 0, (l < L - 1) ? 1 : 0);
        const __half* tmp = hin;
        hin = hout;
        hout = (__half*)tmp;
    }
}